// Round 1
// 303.684 us; speedup vs baseline: 1.0490x; 1.0490x over previous
//
#include <hip/hip_runtime.h>
#include <hip/hip_bf16.h>

#define NNODES 10000
#define NEDGES 320000
#define ETOT   (NEDGES + NNODES)
#define NGRAPH 100
#define CH     250   // HEADS*OUT
#define HOUT   125
#define MPAD   10048 // 157 * 64
#define NTILE  157   // MPAD/64
#define KP0    352   // layer-0 K=336 padded
#define KP1    256   // layers 1-3 K=250 padded
#define HPAD   256   // hb16 row stride (bf16) -> 512B rows
#define ECAP   128   // bucket capacity per node: deg ~ 1+Poisson(32), +16 sigma; guarded
#define DCAPW  128   // per-wave LDS edge cache (== ECAP: cache always covers deg)

typedef __attribute__((ext_vector_type(8))) short bf16x8;
typedef __attribute__((ext_vector_type(4))) float f32x4;

static __device__ __forceinline__ float bflo(unsigned int u){
  union{ unsigned int i; float f; } v; v.i = u << 16; return v.f;
}
static __device__ __forceinline__ float bfhi(unsigned int u){
  union{ unsigned int i; float f; } v; v.i = u & 0xffff0000u; return v.f;
}
static __device__ __forceinline__ unsigned short f2bfbits(float f){
  __hip_bfloat16 b = __float2bfloat16(f);
  union{ __hip_bfloat16 b; unsigned short s; } v; v.b = b; return v.s;
}

struct Args {
  const float* x; const int* eidx; const int* batch;
  const float *W0,*W1,*W2,*W3;
  __hip_bfloat16 *hb16, *Abf0, *Abf, *Wt0, *Wt1, *Wt2, *Wt3;
  int *cursor, *bucket, *gstart;
};

// ---------------- pre: bucketed edge placement + gstart + xconv + wconv ----------------
__global__ void k_pre(Args a){
  int gtid = blockIdx.x * blockDim.x + threadIdx.x;
  int gstr = gridDim.x * blockDim.x;
  for (int e = gtid; e < ETOT; e += gstr){
    int dst, src;
    if (e < NEDGES){ src = a.eidx[e]; dst = a.eidx[NEDGES + e]; }
    else           { src = e - NEDGES; dst = src; }
    int pos = atomicAdd(&a.cursor[dst], 1);
    if (pos < ECAP) a.bucket[(size_t)dst * ECAP + pos] = src;
  }
  for (int n = gtid; n < NNODES; n += gstr){
    int b1 = a.batch[n];
    int b0 = (n == 0) ? -1 : a.batch[n-1];
    for (int b = b0 + 1; b <= b1; ++b) a.gstart[b] = n;
    if (n == NNODES - 1){
      for (int b = b1 + 1; b <= NGRAPH; ++b) a.gstart[b] = NNODES;
    }
  }
  for (int i = gtid; i < NNODES*336; i += gstr){
    int r = i / 336, k = i % 336;
    a.Abf0[(size_t)r * KP0 + k] = __float2bfloat16(a.x[i]);
  }
  const int T0 = 16 * KP0 * 16;
  const int T1 = 16 * KP1 * 16;
  int tot = T0 + 3*T1;
  for (int i = gtid; i < tot; i += gstr){
    const float* W; __hip_bfloat16* Wt; int K, Kp, li;
    if (i < T0)             { W = a.W0; Wt = a.Wt0; K = 336; Kp = KP0; li = i; }
    else if (i < T0 +   T1) { W = a.W1; Wt = a.Wt1; K = CH;  Kp = KP1; li = i - T0; }
    else if (i < T0 + 2*T1) { W = a.W2; Wt = a.Wt2; K = CH;  Kp = KP1; li = i - T0 - T1; }
    else                    { W = a.W3; Wt = a.Wt3; K = CH;  Kp = KP1; li = i - T0 - 2*T1; }
    int KC = Kp >> 5;
    int nt = li / (Kp * 16);
    int rem = li % (Kp * 16);
    int k = rem / 16;
    int n = rem % 16;
    int col = nt * 16 + n;
    float v = (k < K && col < CH) ? W[(size_t)k * CH + col] : 0.f;
    Wt[(((size_t)nt * KC + (k >> 5)) * 16 + n) * 32 + (k & 31)] = __float2bfloat16(v);
  }
}

// ---------------- MFMA GEMM + fused attention scores ----------------
__global__ __launch_bounds__(256) void k_gemm(
    const __hip_bfloat16* __restrict__ A, const __hip_bfloat16* __restrict__ Wt,
    __hip_bfloat16* __restrict__ Cb, const float* __restrict__ asrc,
    const float* __restrict__ adst, float* __restrict__ esrc, float* __restrict__ edst,
    int Kp){
  int wv = threadIdx.x >> 6, lane = threadIdx.x & 63;
  int n16 = lane & 15, q = lane >> 4;
  int KC = Kp >> 5;
  int rowbase = blockIdx.x * 64 + wv * 16;
  int bn = blockIdx.y * 64;
  int nt0 = bn >> 4;
  const __hip_bfloat16* ap = A  + (size_t)(rowbase + n16) * Kp + q * 8;
  const __hip_bfloat16* bp = Wt + ((size_t)nt0 * KC * 16 + n16) * 32 + q * 8;
  f32x4 ac0 = {0.f,0.f,0.f,0.f}, ac1 = ac0, ac2 = ac0, ac3 = ac0;
  for (int kc = 0; kc < KC; ++kc){
    bf16x8 a  = *(const bf16x8*)(ap + (size_t)kc * 32);
    bf16x8 b0 = *(const bf16x8*)(bp + ((size_t)0 * KC + kc) * 512);
    bf16x8 b1 = *(const bf16x8*)(bp + ((size_t)1 * KC + kc) * 512);
    bf16x8 b2 = *(const bf16x8*)(bp + ((size_t)2 * KC + kc) * 512);
    bf16x8 b3 = *(const bf16x8*)(bp + ((size_t)3 * KC + kc) * 512);
    ac0 = __builtin_amdgcn_mfma_f32_16x16x32_bf16(a, b0, ac0, 0, 0, 0);
    ac1 = __builtin_amdgcn_mfma_f32_16x16x32_bf16(a, b1, ac1, 0, 0, 0);
    ac2 = __builtin_amdgcn_mfma_f32_16x16x32_bf16(a, b2, ac2, 0, 0, 0);
    ac3 = __builtin_amdgcn_mfma_f32_16x16x32_bf16(a, b3, ac3, 0, 0, 0);
  }
  float es0[4] = {}, es1[4] = {}, ed0a[4] = {}, ed1a[4] = {};
  #define SCORE_T(AC, T) { \
    int col = bn + (T)*16 + n16; \
    bool ok = col < CH; \
    float av = ok ? asrc[col] : 0.f; \
    float dv = ok ? adst[col] : 0.f; \
    bool hh = col >= HOUT; \
    float av0 = hh ? 0.f : av, av1 = hh ? av : 0.f; \
    float dv0 = hh ? 0.f : dv, dv1 = hh ? dv : 0.f; \
    _Pragma("unroll") \
    for (int r = 0; r < 4; ++r){ \
      es0[r] += AC[r]*av0; es1[r] += AC[r]*av1; \
      ed0a[r] += AC[r]*dv0; ed1a[r] += AC[r]*dv1; } }
  SCORE_T(ac0, 0) SCORE_T(ac1, 1) SCORE_T(ac2, 2) SCORE_T(ac3, 3)
  #undef SCORE_T
  #pragma unroll
  for (int off = 1; off < 16; off <<= 1){
    #pragma unroll
    for (int r = 0; r < 4; ++r){
      es0[r]  += __shfl_xor(es0[r],  off);
      es1[r]  += __shfl_xor(es1[r],  off);
      ed0a[r] += __shfl_xor(ed0a[r], off);
      ed1a[r] += __shfl_xor(ed1a[r], off);
    }
  }
  if (n16 == 0){
    #pragma unroll
    for (int r = 0; r < 4; ++r){
      int row = rowbase + q*4 + r;
      if (row < NNODES){
        atomicAdd(&esrc[row*2+0], es0[r]);
        atomicAdd(&esrc[row*2+1], es1[r]);
        atomicAdd(&edst[row*2+0], ed0a[r]);
        atomicAdd(&edst[row*2+1], ed1a[r]);
      }
    }
  }
  // zero-fill cols >= CH so k_attn's 8-col dwordx4 gather reads clean zeros
  #pragma unroll
  for (int r = 0; r < 4; ++r){
    int row = rowbase + q * 4 + r;
    if (row >= NNODES) continue;
    int col = bn + n16;
    __hip_bfloat16* cb = Cb + (size_t)row * HPAD + col;
    cb[0]  = __float2bfloat16(col      < CH ? ac0[r] : 0.f);
    cb[16] = __float2bfloat16(col + 16 < CH ? ac1[r] : 0.f);
    cb[32] = __float2bfloat16(col + 32 < CH ? ac2[r] : 0.f);
    cb[48] = __float2bfloat16(col + 48 < CH ? ac3[r] : 0.f);
  }
}

// ---------------- fused softmax + gather: wave per node, half-wave edge-parallel ------
// Phase B: lanes 0-31 own cols [8h,8h+8) and walk even edges; lanes 32-63 walk odd
// edges over the same cols. One dwordx4 per lane covers 2 edges per wave-instruction;
// dep-chain length per wave halves vs the 8B/lane variant. Softmax normalization is
// deferred to the epilogue (out = inv * sum(x*h)), halves combined via shfl_xor(32).
__global__ __launch_bounds__(256) void k_attn(const __hip_bfloat16* __restrict__ h,
                        const float* __restrict__ esrc, const float* __restrict__ edst,
                        const int* __restrict__ degv, const int* __restrict__ bucket,
                        const float* __restrict__ bias, __hip_bfloat16* __restrict__ outb,
                        float* __restrict__ esZ, float* __restrict__ edZ){
  int wv = threadIdx.x >> 6, lane = threadIdx.x & 63;
  int node = blockIdx.x * 4 + wv;    // 2500 * 4 == NNODES exactly
  __shared__ int    s_src[4][DCAPW];
  __shared__ float2 s_x[4][DCAPW];
  int deg = degv[node]; if (deg > ECAP) deg = ECAP;
  const int* __restrict__ eb = bucket + (size_t)node * ECAP;
  float ed0 = edst[node*2+0], ed1 = edst[node*2+1];
  // phase A: exp(leaky(e)) -> LDS + wave sum  (deg <= ECAP == DCAPW, cache always covers)
  float sm0 = 0.f, sm1 = 0.f;
  for (int i = lane; i < deg; i += 64){
    int src = eb[i];
    float2 ev = *(const float2*)(esrc + (size_t)src * 2);
    float e0 = ev.x + ed0; e0 = e0 > 0.f ? e0 : 0.2f*e0;
    float e1 = ev.y + ed1; e1 = e1 > 0.f ? e1 : 0.2f*e1;
    float x0 = __expf(e0), x1 = __expf(e1);
    s_src[wv][i] = src; s_x[wv][i] = make_float2(x0, x1);
    sm0 += x0; sm1 += x1;
  }
  #pragma unroll
  for (int off = 32; off > 0; off >>= 1){
    sm0 += __shfl_xor(sm0, off);
    sm1 += __shfl_xor(sm1, off);
  }
  float inv0 = 1.f / (sm0 + 1e-16f);
  float inv1 = 1.f / (sm1 + 1e-16f);
  __syncthreads();   // LDS RAW visibility
  int half = lane >> 5, hl = lane & 31;
  int c0 = hl * 8;                       // 8 cols per lane; cols >= CH are zero in h
  int n0 = HOUT - c0; n0 = n0 < 0 ? 0 : (n0 > 8 ? 8 : n0);   // #head-0 cols of my 8
  const __hip_bfloat16* __restrict__ hrow = h + c0;
  float acc[8] = {0.f,0.f,0.f,0.f,0.f,0.f,0.f,0.f};
  #define EDGE(IDX) { \
    bool vld = (IDX) < deg; \
    int jj = vld ? (IDX) : 0; \
    int s = s_src[wv][jj]; \
    float2 xv = s_x[wv][jj]; \
    float a0 = vld ? xv.x : 0.f; \
    float a1 = vld ? xv.y : 0.f; \
    uint4 d = *(const uint4*)(hrow + (size_t)s * HPAD); \
    acc[0] += (0 < n0 ? a0 : a1) * bflo(d.x); \
    acc[1] += (1 < n0 ? a0 : a1) * bfhi(d.x); \
    acc[2] += (2 < n0 ? a0 : a1) * bflo(d.y); \
    acc[3] += (3 < n0 ? a0 : a1) * bfhi(d.y); \
    acc[4] += (4 < n0 ? a0 : a1) * bflo(d.z); \
    acc[5] += (5 < n0 ? a0 : a1) * bfhi(d.z); \
    acc[6] += (6 < n0 ? a0 : a1) * bflo(d.w); \
    acc[7] += (7 < n0 ? a0 : a1) * bfhi(d.w); }
  for (int it = half; it < deg; it += 4){
    EDGE(it)
    EDGE(it + 2)
  }
  #undef EDGE
  #pragma unroll
  for (int j = 0; j < 8; ++j) acc[j] += __shfl_xor(acc[j], 32);
  if (half == 0){
    if (hl < 31){
      float4 bA = *(const float4*)&bias[c0];
      float4 bB = *(const float4*)&bias[c0 + 4];
      float v0 = acc[0]*(0 < n0 ? inv0 : inv1) + bA.x;
      float v1 = acc[1]*(1 < n0 ? inv0 : inv1) + bA.y;
      float v2 = acc[2]*(2 < n0 ? inv0 : inv1) + bA.z;
      float v3 = acc[3]*(3 < n0 ? inv0 : inv1) + bA.w;
      float v4 = acc[4]*(4 < n0 ? inv0 : inv1) + bB.x;
      float v5 = acc[5]*(5 < n0 ? inv0 : inv1) + bB.y;
      float v6 = acc[6]*(6 < n0 ? inv0 : inv1) + bB.z;
      float v7 = acc[7]*(7 < n0 ? inv0 : inv1) + bB.w;
      v0 = v0 > 0.f ? v0 : 0.f; v1 = v1 > 0.f ? v1 : 0.f;
      v2 = v2 > 0.f ? v2 : 0.f; v3 = v3 > 0.f ? v3 : 0.f;
      v4 = v4 > 0.f ? v4 : 0.f; v5 = v5 > 0.f ? v5 : 0.f;
      v6 = v6 > 0.f ? v6 : 0.f; v7 = v7 > 0.f ? v7 : 0.f;
      uint4 o;
      o.x = (unsigned int)f2bfbits(v0) | ((unsigned int)f2bfbits(v1) << 16);
      o.y = (unsigned int)f2bfbits(v2) | ((unsigned int)f2bfbits(v3) << 16);
      o.z = (unsigned int)f2bfbits(v4) | ((unsigned int)f2bfbits(v5) << 16);
      o.w = (unsigned int)f2bfbits(v6) | ((unsigned int)f2bfbits(v7) << 16);
      *(uint4*)(outb + (size_t)node * KP1 + c0) = o;
    } else {
      float v0 = acc[0]*inv1 + bias[248];      // cols 248,249 are head-1
      float v1 = acc[1]*inv1 + bias[249];
      v0 = v0 > 0.f ? v0 : 0.f; v1 = v1 > 0.f ? v1 : 0.f;
      unsigned int o = (unsigned int)f2bfbits(v0) | ((unsigned int)f2bfbits(v1) << 16);
      *(unsigned int*)(outb + (size_t)node * KP1 + 248) = o;
    }
  }
  if (lane < 2){   // prep next layer's score accumulators
    esZ[node*2 + lane] = 0.f;
    edZ[node*2 + lane] = 0.f;
  }
}

// ---------------- fused head: segmented mean pool (bf16 input) + 4-layer MLP -------------
__global__ __launch_bounds__(256) void k_head(const __hip_bfloat16* __restrict__ xb,
                        const int* __restrict__ gstart,
                        const float* __restrict__ lw1, const float* __restrict__ lb1,
                        const float* __restrict__ lw2, const float* __restrict__ lb2,
                        const float* __restrict__ lw3, const float* __restrict__ lb3,
                        const float* __restrict__ lw4, const float* __restrict__ lb4,
                        float* __restrict__ out){
  int g = blockIdx.x;
  int tid = threadIdx.x;
  int s = gstart[g], e = gstart[g+1];
  __shared__ float gvec[256];
  __shared__ float m1[200];
  __shared__ float m2[112];
  __shared__ float m3[112];
  if (tid < 128){
    int c2 = tid * 2;                          // 2 bf16 cols per thread, 4B loads
    const __hip_bfloat16* xp = xb + c2;
    float a0=0.f,a1=0.f,b0=0.f,b1=0.f;
    int n = s;
    for (; n + 3 < e; n += 4){
      unsigned int u0 = *(const unsigned int*)(xp + (size_t)n     * KP1);
      unsigned int u1 = *(const unsigned int*)(xp + (size_t)(n+1) * KP1);
      unsigned int u2 = *(const unsigned int*)(xp + (size_t)(n+2) * KP1);
      unsigned int u3 = *(const unsigned int*)(xp + (size_t)(n+3) * KP1);
      a0 += bflo(u0) + bflo(u2); a1 += bfhi(u0) + bfhi(u2);
      b0 += bflo(u1) + bflo(u3); b1 += bfhi(u1) + bfhi(u3);
    }
    for (; n < e; ++n){
      unsigned int u0 = *(const unsigned int*)(xp + (size_t)n * KP1);
      a0 += bflo(u0); a1 += bfhi(u0);
    }
    float scale = 1.f / fmaxf((float)(e - s), 1.f);
    gvec[c2]     = (a0 + b0) * scale;
    gvec[c2 + 1] = (a1 + b1) * scale;
  }
  __syncthreads();
  if (tid < 200){
    float a0=0.f,a1=0.f,a2=0.f,a3=0.f;
    int k = 0;
    for (; k + 3 < CH; k += 4){
      a0 += gvec[k]   * lw1[(size_t)k     * 200 + tid];
      a1 += gvec[k+1] * lw1[(size_t)(k+1) * 200 + tid];
      a2 += gvec[k+2] * lw1[(size_t)(k+2) * 200 + tid];
      a3 += gvec[k+3] * lw1[(size_t)(k+3) * 200 + tid];
    }
    for (; k < CH; ++k) a0 += gvec[k] * lw1[(size_t)k * 200 + tid];
    float v = a0 + a1 + a2 + a3 + lb1[tid];
    m1[tid] = v > 0.f ? v : 0.f;
  }
  __syncthreads();
  if (tid < 100){
    float a0=0.f,a1=0.f,a2=0.f,a3=0.f;
    for (int k = 0; k + 3 < 200; k += 4){
      a0 += m1[k]   * lw2[(size_t)k     * 100 + tid];
      a1 += m1[k+1] * lw2[(size_t)(k+1) * 100 + tid];
      a2 += m1[k+2] * lw2[(size_t)(k+2) * 100 + tid];
      a3 += m1[k+3] * lw2[(size_t)(k+3) * 100 + tid];
    }
    float v = a0 + a1 + a2 + a3 + lb2[tid];
    m2[tid] = v > 0.f ? v : 0.f;
  }
  __syncthreads();
  if (tid < 100){
    float a0=0.f,a1=0.f,a2=0.f,a3=0.f;
    for (int k = 0; k + 3 < 100; k += 4){
      a0 += m2[k]   * lw3[(size_t)k     * 100 + tid];
      a1 += m2[k+1] * lw3[(size_t)(k+1) * 100 + tid];
      a2 += m2[k+2] * lw3[(size_t)(k+2) * 100 + tid];
      a3 += m2[k+3] * lw3[(size_t)(k+3) * 100 + tid];
    }
    float v = a0 + a1 + a2 + a3 + lb3[tid];
    m3[tid] = v > 0.f ? v : 0.f;
  }
  __syncthreads();
  if (tid < 29){
    float a0=0.f,a1=0.f,a2=0.f,a3=0.f;
    for (int k = 0; k + 3 < 100; k += 4){
      a0 += m3[k]   * lw4[(size_t)k     * 29 + tid];
      a1 += m3[k+1] * lw4[(size_t)(k+1) * 29 + tid];
      a2 += m3[k+2] * lw4[(size_t)(k+2) * 29 + tid];
      a3 += m3[k+3] * lw4[(size_t)(k+3) * 29 + tid];
    }
    out[(size_t)g * 29 + tid] = a0 + a1 + a2 + a3 + lb4[tid];
  }
}

// ---------------- launch ----------------
extern "C" void kernel_launch(void* const* d_in, const int* in_sizes, int n_in,
                              void* d_out, int out_size, void* d_ws, size_t ws_size,
                              hipStream_t stream){
  char* ws = (char*)d_ws;
  size_t off = 0;
  auto alloc = [&](size_t bytes)->void*{
    void* p = ws + off;
    off = (off + bytes + 255) & ~(size_t)255;
    return p;
  };
  __hip_bfloat16* hb16 = (__hip_bfloat16*)alloc((size_t)NNODES * HPAD * 2);
  __hip_bfloat16* Abf0 = (__hip_bfloat16*)alloc((size_t)MPAD * KP0 * 2);
  __hip_bfloat16* Abf  = (__hip_bfloat16*)alloc((size_t)MPAD * KP1 * 2);
  __hip_bfloat16* Wt0  = (__hip_bfloat16*)alloc((size_t)16 * KP0 * 16 * 2);
  __hip_bfloat16* Wt1  = (__hip_bfloat16*)alloc((size_t)16 * KP1 * 16 * 2);
  __hip_bfloat16* Wt2  = (__hip_bfloat16*)alloc((size_t)16 * KP1 * 16 * 2);
  __hip_bfloat16* Wt3  = (__hip_bfloat16*)alloc((size_t)16 * KP1 * 16 * 2);
  size_t zbeg = off;
  int*   cursor = (int*)  alloc((size_t)NNODES * 4);      // doubles as deg
  float* esA  = (float*)alloc((size_t)NNODES * 2 * 4);
  float* edA  = (float*)alloc((size_t)NNODES * 2 * 4);
  size_t zend = off;
  float* esB  = (float*)alloc((size_t)NNODES * 2 * 4);    // zeroed by attn L0
  float* edB  = (float*)alloc((size_t)NNODES * 2 * 4);
  int*   bucket = (int*)alloc((size_t)NNODES * ECAP * 4);
  int*   gstart = (int*)alloc((size_t)(NGRAPH + 1) * 4);

  hipMemsetAsync(ws + zbeg, 0, zend - zbeg, stream);

  Args a;
  a.x = (const float*)d_in[0];
  a.eidx = (const int*)d_in[1];
  a.batch = (const int*)d_in[2];
  a.W0 = (const float*)d_in[3];  a.W1 = (const float*)d_in[7];
  a.W2 = (const float*)d_in[11]; a.W3 = (const float*)d_in[15];
  a.hb16 = hb16; a.Abf0 = Abf0; a.Abf = Abf;
  a.Wt0 = Wt0; a.Wt1 = Wt1; a.Wt2 = Wt2; a.Wt3 = Wt3;
  a.cursor = cursor; a.bucket = bucket; a.gstart = gstart;

  k_pre<<<(ETOT + 255)/256, 256, 0, stream>>>(a);

  const __hip_bfloat16* Wts[4] = {Wt0, Wt1, Wt2, Wt3};
  for (int L = 0; L < 4; ++L){
    const float* as_ = (const float*)d_in[4 + 4*L];
    const float* ad_ = (const float*)d_in[5 + 4*L];
    const float* bb  = (const float*)d_in[6 + 4*L];
    int Kp = (L == 0) ? KP0 : KP1;
    const __hip_bfloat16* Ain = (L == 0) ? Abf0 : Abf;
    float* es  = (L & 1) ? esB : esA;
    float* ed  = (L & 1) ? edB : edA;
    float* esZ = (L & 1) ? esA : esB;
    float* edZ = (L & 1) ? edA : edB;

    k_gemm<<<dim3(NTILE, 4), 256, 0, stream>>>(Ain, Wts[L], hb16, as_, ad_, es, ed, Kp);
    k_attn<<<NNODES/4, 256, 0, stream>>>(hb16, es, ed, cursor, bucket, bb, Abf, esZ, edZ);
  }

  k_head<<<NGRAPH, 256, 0, stream>>>(Abf, gstart,
      (const float*)d_in[19], (const float*)d_in[20],
      (const float*)d_in[21], (const float*)d_in[22],
      (const float*)d_in[23], (const float*)d_in[24],
      (const float*)d_in[25], (const float*)d_in[26],
      (float*)d_out);
}